// Round 3
// baseline (858.388 us; speedup 1.0000x reference)
//
#include <hip/hip_runtime.h>

#define N_POINTS 500000
#define K_CENT   512
#define W_DIM    64
#define N_JOBS   ((N_POINTS + 63) / 64)   // 7813 (last job: only tile0 valid)
#define SCALE_LO 2048.0f                  // 2^11
#define INV_LO   (1.0f / 2048.0f)

typedef _Float16 half8 __attribute__((ext_vector_type(8)));
typedef float    f32x16 __attribute__((ext_vector_type(16)));

// ---- pre-kernel 1: codebook -> f16 hi/lo of w = -2*c (lo pre-scaled by 2^11)
__global__ void cvt_kernel(const float* __restrict__ cb,
                           _Float16* __restrict__ cb_h,
                           _Float16* __restrict__ cb_l) {
    int id = blockIdx.x * 256 + threadIdx.x;           // 512*8 = 4096 ids
    if (id >= K_CENT * 8) return;
    int c = id >> 3, o = (id & 7) * 8;
    const float* src = cb + (size_t)c * W_DIM + o;
    half8 h, l;
#pragma unroll
    for (int j = 0; j < 8; ++j) {
        float w = -2.0f * src[j];
        _Float16 hh = (_Float16)w;                     // RNE
        h[j] = hh;
        l[j] = (_Float16)((w - (float)hh) * SCALE_LO); // residual, scaled up
    }
    *(half8*)(cb_h + (size_t)c * W_DIM + o) = h;
    *(half8*)(cb_l + (size_t)c * W_DIM + o) = l;
}

// ---- pre-kernel 2: c2[c] = ||c||^2 in double (deterministic)
__global__ void c2_kernel(const float* __restrict__ cb, float* __restrict__ c2) {
    int c = blockIdx.x * 256 + threadIdx.x;
    if (c >= K_CENT) return;
    const float4* row = (const float4*)(cb + (size_t)c * W_DIM);
    double s = 0.0;
#pragma unroll
    for (int j = 0; j < W_DIM / 4; ++j) {
        float4 v = row[j];
        s += (double)v.x * v.x + (double)v.y * v.y + (double)v.z * v.z + (double)v.w * v.w;
    }
    c2[c] = (float)s;
}

// ---- main kernel: per wave, TWO 32-point tiles vs all 512 centroids.
// A = codebook chunk (32 cent x 16 dims) shared by both tiles -> 4 independent
// accumulator chains per chunk (24 MFMAs), halved A traffic per point.
// mfma_f32_32x32x16_f16 layouts (verified R2): A lane l: row=l&31, k=(l>>5)*8+j;
// B: col=l&31, k=(l>>5)*8+j; C/D: col=l&31, row=(reg&3)+8*(reg>>2)+4*(l>>5).
__global__ __launch_bounds__(256, 2)
void kmeans_mfma(const float* __restrict__ X,
                 const _Float16* __restrict__ cb_h,
                 const _Float16* __restrict__ cb_l,
                 const float* __restrict__ c2,
                 float* __restrict__ out_idx,
                 float* __restrict__ out_dist) {
    __shared__ float c2s[K_CENT];
    int tid = threadIdx.x;
    c2s[tid] = c2[tid];
    c2s[tid + 256] = c2[tid + 256];
    __syncthreads();

    int lane = tid & 63;
    int wave = tid >> 6;
    int half = lane >> 5;      // 0/1
    int l31  = lane & 31;
    int kb   = half * 8;       // k-offset within a K=16 step

    int job = blockIdx.x * 4 + wave;
    if (job >= N_JOBS) return;

    int  p0 = job * 64 + l31;
    bool v1 = (job * 64 + 32) < N_POINTS;   // tile1 fully valid iff job < 7812
    int  p1 = v1 ? (p0 + 32) : p0;          // safe load address when invalid

    // ---- load + convert both X tiles (B operands): f16 hi + scaled lo
    half8 b0h[4], b0l[4], b1h[4], b1l[4];
    float x20 = 0.f, x21 = 0.f;
#pragma unroll
    for (int s = 0; s < 4; ++s) {
        const float4* xa = (const float4*)(X + (size_t)p0 * W_DIM + s * 16 + kb);
        float4 f0 = xa[0], f1 = xa[1];
        float fa[8] = {f0.x, f0.y, f0.z, f0.w, f1.x, f1.y, f1.z, f1.w};
        const float4* xb = (const float4*)(X + (size_t)p1 * W_DIM + s * 16 + kb);
        float4 g0 = xb[0], g1 = xb[1];
        float fb[8] = {g0.x, g0.y, g0.z, g0.w, g1.x, g1.y, g1.z, g1.w};
#pragma unroll
        for (int j = 0; j < 8; ++j) {
            _Float16 h0 = (_Float16)fa[j];
            b0h[s][j] = h0;
            b0l[s][j] = (_Float16)((fa[j] - (float)h0) * SCALE_LO);
            x20 = fmaf(fa[j], fa[j], x20);
            _Float16 h1 = (_Float16)fb[j];
            b1h[s][j] = h1;
            b1l[s][j] = (_Float16)((fb[j] - (float)h1) * SCALE_LO);
            x21 = fmaf(fb[j], fb[j], x21);
        }
    }
    x20 += __shfl_xor(x20, 32);   // halves hold disjoint dim sets of same point
    x21 += __shfl_xor(x21, 32);

    float bd0 = 3.4e38f, bd1 = 3.4e38f;
    int   bi0 = 0,       bi1 = 0;

    // A-fragment double buffers
    half8 ah[2][4], al[2][4];
    const _Float16* ab_h = cb_h + (size_t)l31 * W_DIM + kb;
    const _Float16* ab_l = cb_l + (size_t)l31 * W_DIM + kb;
#pragma unroll
    for (int s = 0; s < 4; ++s) {
        ah[0][s] = *(const half8*)(ab_h + s * 16);
        al[0][s] = *(const half8*)(ab_l + s * 16);
    }

#pragma unroll
    for (int t = 0; t < 16; ++t) {
        int cur = t & 1, nxt = cur ^ 1;
        if (t < 15) {
            const _Float16* nh = ab_h + (size_t)(t + 1) * 32 * W_DIM;
            const _Float16* nl = ab_l + (size_t)(t + 1) * 32 * W_DIM;
#pragma unroll
            for (int s = 0; s < 4; ++s) {
                ah[nxt][s] = *(const half8*)(nh + s * 16);
                al[nxt][s] = *(const half8*)(nl + s * 16);
            }
        }
        // acc init: both tiles share the same centroid chunk -> same c2 init
        float4 q0 = *(const float4*)&c2s[t * 32 + half * 4 + 0];
        float4 q1 = *(const float4*)&c2s[t * 32 + half * 4 + 8];
        float4 q2 = *(const float4*)&c2s[t * 32 + half * 4 + 16];
        float4 q3 = *(const float4*)&c2s[t * 32 + half * 4 + 24];
        f32x16 am0, am1, ac0, ac1;
        am0[0]=q0.x; am0[1]=q0.y; am0[2]=q0.z; am0[3]=q0.w;
        am0[4]=q1.x; am0[5]=q1.y; am0[6]=q1.z; am0[7]=q1.w;
        am0[8]=q2.x; am0[9]=q2.y; am0[10]=q2.z; am0[11]=q2.w;
        am0[12]=q3.x; am0[13]=q3.y; am0[14]=q3.z; am0[15]=q3.w;
        am1 = am0;
#pragma unroll
        for (int j = 0; j < 16; ++j) { ac0[j] = 0.f; ac1[j] = 0.f; }

#pragma unroll
        for (int s = 0; s < 4; ++s) {
            am0 = __builtin_amdgcn_mfma_f32_32x32x16_f16(ah[cur][s], b0h[s], am0, 0, 0, 0);
            am1 = __builtin_amdgcn_mfma_f32_32x32x16_f16(ah[cur][s], b1h[s], am1, 0, 0, 0);
            ac0 = __builtin_amdgcn_mfma_f32_32x32x16_f16(al[cur][s], b0h[s], ac0, 0, 0, 0);
            ac1 = __builtin_amdgcn_mfma_f32_32x32x16_f16(al[cur][s], b1h[s], ac1, 0, 0, 0);
            ac0 = __builtin_amdgcn_mfma_f32_32x32x16_f16(ah[cur][s], b0l[s], ac0, 0, 0, 0);
            ac1 = __builtin_amdgcn_mfma_f32_32x32x16_f16(ah[cur][s], b1l[s], ac1, 0, 0, 0);
        }
        // argmin: acc reg j -> centroid t*32 + 4*half + 8*(j>>2) + (j&3)
#pragma unroll
        for (int j = 0; j < 16; ++j) {
            int ci = t * 32 + half * 4 + (j >> 2) * 8 + (j & 3);
            float v0 = fmaf(ac0[j], INV_LO, am0[j]);   // d2 - x2
            if (v0 < bd0) { bd0 = v0; bi0 = ci; }      // strict <: first-index wins
            float v1d = fmaf(ac1[j], INV_LO, am1[j]);
            if (v1d < bd1) { bd1 = v1d; bi1 = ci; }
        }
    }

    // combine the two lane-halves (disjoint centroid rows of the same point)
    {
        float od = __shfl_xor(bd0, 32); int oi = __shfl_xor(bi0, 32);
        if (od < bd0 || (od == bd0 && oi < bi0)) { bd0 = od; bi0 = oi; }
        od = __shfl_xor(bd1, 32); oi = __shfl_xor(bi1, 32);
        if (od < bd1 || (od == bd1 && oi < bi1)) { bd1 = od; bi1 = oi; }
    }

    if (half == 0) {
        out_idx[p0]  = (float)bi0;
        out_dist[p0] = sqrtf(fmaxf(bd0 + x20, 0.f));
        if (v1) {
            out_idx[p1]  = (float)bi1;
            out_dist[p1] = sqrtf(fmaxf(bd1 + x21, 0.f));
        }
    }
}

extern "C" void kernel_launch(void* const* d_in, const int* in_sizes, int n_in,
                              void* d_out, int out_size, void* d_ws, size_t ws_size,
                              hipStream_t stream) {
    const float* X  = (const float*)d_in[0];
    const float* cb = (const float*)d_in[1];
    float* out      = (float*)d_out;

    // workspace layout: cb_h 64KB | cb_l 64KB | c2 2KB
    _Float16* cb_h = (_Float16*)d_ws;
    _Float16* cb_l = cb_h + (size_t)K_CENT * W_DIM;
    float*    c2   = (float*)(cb_l + (size_t)K_CENT * W_DIM);

    hipLaunchKernelGGL(cvt_kernel, dim3((K_CENT * 8 + 255) / 256), dim3(256), 0, stream, cb, cb_h, cb_l);
    hipLaunchKernelGGL(c2_kernel, dim3((K_CENT + 255) / 256), dim3(256), 0, stream, cb, c2);

    int grid = (N_JOBS + 3) / 4;   // 4 wave-jobs (8 tiles) per 256-thread block
    hipLaunchKernelGGL(kmeans_mfma, dim3(grid), dim3(256), 0, stream,
                       X, cb_h, cb_l, c2, out, out + N_POINTS);
}

// Round 4
// 118.960 us; speedup vs baseline: 7.2158x; 7.2158x over previous
//
#include <hip/hip_runtime.h>

#define N_POINTS 500000
#define K_CENT   512
#define W_DIM    64
#define N_JOBS   ((N_POINTS + 63) / 64)   // 7813 (last job: tile1 invalid)
#define SCALE_LO 2048.0f                  // 2^11
#define INV_LO   (1.0f / 2048.0f)

typedef _Float16 half8 __attribute__((ext_vector_type(8)));
typedef float    f32x16 __attribute__((ext_vector_type(16)));

// ---- pre-kernel 1: codebook -> fragment-ordered f16 hi/lo planes of w = -2*c.
// Layout (halves): [t:16][plane:2][s:4][lane:64][j:8]  -> per chunk 8 KB, total 128 KB.
// A-fragment mapping (mfma_f32_32x32x16_f16, verified R2): lane l holds
// row=l&31, k=(l>>5)*8+j of the K=16 step s  => centroid c = t*32+(l&31),
// dim d = s*16 + (l>>5)*8 + j.
__global__ void cvt_kernel(const float* __restrict__ cb,
                           _Float16* __restrict__ cbf) {
    int id = blockIdx.x * 256 + threadIdx.x;           // 4096 ids
    if (id >= K_CENT * 8) return;
    int c = id >> 3, o = (id & 7) * 8;                 // centroid, dim base
    int t = c >> 5, r = c & 31;
    int s = o >> 4, half = (o >> 3) & 1;
    int lane = half * 32 + r;
    const float* src = cb + (size_t)c * W_DIM + o;
    half8 h, l;
#pragma unroll
    for (int j = 0; j < 8; ++j) {
        float w = -2.0f * src[j];
        _Float16 hh = (_Float16)w;                     // RNE
        h[j] = hh;
        l[j] = (_Float16)((w - (float)hh) * SCALE_LO); // residual, scaled 2^11
    }
    size_t base_h = ((size_t)(t * 2 + 0) * 4 + s) * 512 + (size_t)lane * 8;
    size_t base_l = ((size_t)(t * 2 + 1) * 4 + s) * 512 + (size_t)lane * 8;
    *(half8*)(cbf + base_h) = h;
    *(half8*)(cbf + base_l) = l;
}

// ---- pre-kernel 2: c2[c] = ||c||^2 in double (deterministic)
__global__ void c2_kernel(const float* __restrict__ cb, float* __restrict__ c2) {
    int c = blockIdx.x * 256 + threadIdx.x;
    if (c >= K_CENT) return;
    const float4* row = (const float4*)(cb + (size_t)c * W_DIM);
    double s = 0.0;
#pragma unroll
    for (int j = 0; j < W_DIM / 4; ++j) {
        float4 v = row[j];
        s += (double)v.x * v.x + (double)v.y * v.y + (double)v.z * v.z + (double)v.w * v.w;
    }
    c2[c] = (float)s;
}

// One chunk of 32 centroids vs both 32-point tiles. CURH/CURL were prefetched;
// prefetch NXTH/NXTL for chunk t+1. All register indices compile-time.
#define CHUNK_BODY(T, CURH, CURL, NXTH, NXTL)                                      \
    {                                                                              \
        int t_ = (T);                                                              \
        if (t_ < 15) {                                                             \
            const _Float16* nb = cbf + (size_t)(t_ + 1) * 4096 + (size_t)lane * 8; \
            NXTH[0] = *(const half8*)(nb + 0 * 512);                               \
            NXTH[1] = *(const half8*)(nb + 1 * 512);                               \
            NXTH[2] = *(const half8*)(nb + 2 * 512);                               \
            NXTH[3] = *(const half8*)(nb + 3 * 512);                               \
            NXTL[0] = *(const half8*)(nb + 2048 + 0 * 512);                        \
            NXTL[1] = *(const half8*)(nb + 2048 + 1 * 512);                        \
            NXTL[2] = *(const half8*)(nb + 2048 + 2 * 512);                        \
            NXTL[3] = *(const half8*)(nb + 2048 + 3 * 512);                        \
        }                                                                          \
        float4 q0 = *(const float4*)&c2s[t_ * 32 + half * 4 + 0];                  \
        float4 q1 = *(const float4*)&c2s[t_ * 32 + half * 4 + 8];                  \
        float4 q2 = *(const float4*)&c2s[t_ * 32 + half * 4 + 16];                 \
        float4 q3 = *(const float4*)&c2s[t_ * 32 + half * 4 + 24];                 \
        f32x16 am0, am1, ac0, ac1;                                                 \
        am0[0]=q0.x; am0[1]=q0.y; am0[2]=q0.z; am0[3]=q0.w;                        \
        am0[4]=q1.x; am0[5]=q1.y; am0[6]=q1.z; am0[7]=q1.w;                        \
        am0[8]=q2.x; am0[9]=q2.y; am0[10]=q2.z; am0[11]=q2.w;                      \
        am0[12]=q3.x; am0[13]=q3.y; am0[14]=q3.z; am0[15]=q3.w;                    \
        am1 = am0;                                                                 \
        _Pragma("unroll")                                                          \
        for (int j = 0; j < 16; ++j) { ac0[j] = 0.f; ac1[j] = 0.f; }               \
        _Pragma("unroll")                                                          \
        for (int s = 0; s < 4; ++s) {                                              \
            am0 = __builtin_amdgcn_mfma_f32_32x32x16_f16(CURH[s], b0h[s], am0, 0, 0, 0); \
            am1 = __builtin_amdgcn_mfma_f32_32x32x16_f16(CURH[s], b1h[s], am1, 0, 0, 0); \
            ac0 = __builtin_amdgcn_mfma_f32_32x32x16_f16(CURL[s], b0h[s], ac0, 0, 0, 0); \
            ac1 = __builtin_amdgcn_mfma_f32_32x32x16_f16(CURL[s], b1h[s], ac1, 0, 0, 0); \
            ac0 = __builtin_amdgcn_mfma_f32_32x32x16_f16(CURH[s], b0l[s], ac0, 0, 0, 0); \
            ac1 = __builtin_amdgcn_mfma_f32_32x32x16_f16(CURH[s], b1l[s], ac1, 0, 0, 0); \
        }                                                                          \
        _Pragma("unroll")                                                          \
        for (int j = 0; j < 16; ++j) {                                             \
            int ci = t_ * 32 + half * 4 + (j >> 2) * 8 + (j & 3);                  \
            float v0 = fmaf(ac0[j], INV_LO, am0[j]);                               \
            if (v0 < bd0) { bd0 = v0; bi0 = ci; }                                  \
            float v1d = fmaf(ac1[j], INV_LO, am1[j]);                              \
            if (v1d < bd1) { bd1 = v1d; bi1 = ci; }                                \
        }                                                                          \
    }

// ---- main kernel: one wave per block; TWO 32-point tiles vs all 512 centroids.
__global__ __launch_bounds__(64, 2)
void kmeans_mfma(const float* __restrict__ X,
                 const _Float16* __restrict__ cbf,
                 const float* __restrict__ c2,
                 float* __restrict__ out_idx,
                 float* __restrict__ out_dist) {
    __shared__ float c2s[K_CENT];
    int lane = threadIdx.x;         // 0..63
#pragma unroll
    for (int i = 0; i < 8; ++i) c2s[lane + 64 * i] = c2[lane + 64 * i];
    __syncthreads();

    int half = lane >> 5;           // 0/1
    int l31  = lane & 31;
    int kb   = half * 8;

    int job = blockIdx.x;           // grid = N_JOBS exactly
    int  p0 = job * 64 + l31;
    bool v1 = (job * 64 + 32) < N_POINTS;
    int  p1 = v1 ? (p0 + 32) : p0;

    // ---- load + convert both X tiles (B operands): f16 hi + scaled lo
    half8 b0h[4], b0l[4], b1h[4], b1l[4];
    float x20 = 0.f, x21 = 0.f;
#pragma unroll
    for (int s = 0; s < 4; ++s) {
        const float4* xa = (const float4*)(X + (size_t)p0 * W_DIM + s * 16 + kb);
        float4 f0 = xa[0], f1 = xa[1];
        float fa[8] = {f0.x, f0.y, f0.z, f0.w, f1.x, f1.y, f1.z, f1.w};
        const float4* xb = (const float4*)(X + (size_t)p1 * W_DIM + s * 16 + kb);
        float4 g0 = xb[0], g1 = xb[1];
        float fb[8] = {g0.x, g0.y, g0.z, g0.w, g1.x, g1.y, g1.z, g1.w};
#pragma unroll
        for (int j = 0; j < 8; ++j) {
            _Float16 h0 = (_Float16)fa[j];
            b0h[s][j] = h0;
            b0l[s][j] = (_Float16)((fa[j] - (float)h0) * SCALE_LO);
            x20 = fmaf(fa[j], fa[j], x20);
            _Float16 h1 = (_Float16)fb[j];
            b1h[s][j] = h1;
            b1l[s][j] = (_Float16)((fb[j] - (float)h1) * SCALE_LO);
            x21 = fmaf(fb[j], fb[j], x21);
        }
    }
    x20 += __shfl_xor(x20, 32);     // halves hold disjoint dims of same point
    x21 += __shfl_xor(x21, 32);

    float bd0 = 3.4e38f, bd1 = 3.4e38f;
    int   bi0 = 0,       bi1 = 0;

    // A-fragment double buffers as NAMED register sets (no runtime indexing)
    half8 ahA[4], alA[4], ahB[4], alB[4];
    {
        const _Float16* ab = cbf + (size_t)lane * 8;
        ahA[0] = *(const half8*)(ab + 0 * 512);
        ahA[1] = *(const half8*)(ab + 1 * 512);
        ahA[2] = *(const half8*)(ab + 2 * 512);
        ahA[3] = *(const half8*)(ab + 3 * 512);
        alA[0] = *(const half8*)(ab + 2048 + 0 * 512);
        alA[1] = *(const half8*)(ab + 2048 + 1 * 512);
        alA[2] = *(const half8*)(ab + 2048 + 2 * 512);
        alA[3] = *(const half8*)(ab + 2048 + 3 * 512);
    }

#pragma unroll 1
    for (int tt = 0; tt < 8; ++tt) {
        CHUNK_BODY(2 * tt,     ahA, alA, ahB, alB)
        CHUNK_BODY(2 * tt + 1, ahB, alB, ahA, alA)
    }

    // combine the two lane-halves (disjoint centroid rows of the same point)
    {
        float od = __shfl_xor(bd0, 32); int oi = __shfl_xor(bi0, 32);
        if (od < bd0 || (od == bd0 && oi < bi0)) { bd0 = od; bi0 = oi; }
        od = __shfl_xor(bd1, 32); oi = __shfl_xor(bi1, 32);
        if (od < bd1 || (od == bd1 && oi < bi1)) { bd1 = od; bi1 = oi; }
    }

    if (half == 0) {
        out_idx[p0]  = (float)bi0;
        out_dist[p0] = sqrtf(fmaxf(bd0 + x20, 0.f));
        if (v1) {
            out_idx[p1]  = (float)bi1;
            out_dist[p1] = sqrtf(fmaxf(bd1 + x21, 0.f));
        }
    }
}

extern "C" void kernel_launch(void* const* d_in, const int* in_sizes, int n_in,
                              void* d_out, int out_size, void* d_ws, size_t ws_size,
                              hipStream_t stream) {
    const float* X  = (const float*)d_in[0];
    const float* cb = (const float*)d_in[1];
    float* out      = (float*)d_out;

    // workspace: fragment-ordered codebook 128KB | c2 2KB
    _Float16* cbf = (_Float16*)d_ws;
    float*    c2  = (float*)(cbf + (size_t)K_CENT * W_DIM * 2);

    hipLaunchKernelGGL(cvt_kernel, dim3((K_CENT * 8 + 255) / 256), dim3(256), 0, stream, cb, cbf);
    hipLaunchKernelGGL(c2_kernel, dim3((K_CENT + 255) / 256), dim3(256), 0, stream, cb, c2);

    hipLaunchKernelGGL(kmeans_mfma, dim3(N_JOBS), dim3(64), 0, stream,
                       X, cbf, c2, out, out + N_POINTS);
}